// Round 1
// baseline (794.993 us; speedup 1.0000x reference)
//
#include <hip/hip_runtime.h>
#include <hip/hip_bf16.h>
#include <math.h>

// Problem constants (validated against in_sizes at launch)
#define D_IN   128
#define D_RNI  32
#define HID    256

// ---------------------------------------------------------------------------
// Edge dtype detection: reference declares int64, but JAX without x64 yields
// int32. For int64 (values < 2^31), every odd 32-bit word is 0. Sample the
// first 1024 odd words; OR==0 => int64 (mode=1), else int32 (mode=0).
// ---------------------------------------------------------------------------
__global__ void k_detect(const unsigned int* __restrict__ w, int nwords, int* __restrict__ mode) {
    __shared__ unsigned int red[256];
    unsigned int acc = 0;
    for (int i = threadIdx.x; i < 1024; i += 256) {
        int idx = 2 * i + 1;
        if (idx < nwords) acc |= w[idx];
    }
    red[threadIdx.x] = acc;
    __syncthreads();
    for (int s = 128; s > 0; s >>= 1) {
        if (threadIdx.x < s) red[threadIdx.x] |= red[threadIdx.x + s];
        __syncthreads();
    }
    if (threadIdx.x == 0) *mode = (red[0] == 0u) ? 1 : 0;
}

// counts[dst]++ for every edge
__global__ void k_count(const unsigned int* __restrict__ ew, const int* __restrict__ mode_p,
                        int* __restrict__ counts, int e) {
    int mode = *mode_p;
    int i = blockIdx.x * 256 + threadIdx.x;
    if (i >= e) return;
    int d = mode ? (int)ew[2 * ((size_t)e + i)] : (int)ew[(size_t)e + i];
    atomicAdd(&counts[d], 1);
}

// Single-block exclusive scan over counts -> rowptr, cursor; dis = 1/sqrt(deg+1)
__global__ __launch_bounds__(1024) void k_scan(const int* __restrict__ counts,
                                               int* __restrict__ rowptr,
                                               int* __restrict__ cursor,
                                               float* __restrict__ dis, int n) {
    __shared__ int sd[1024];
    int carry = 0;
    int t = threadIdx.x;
    for (int base = 0; base < n; base += 1024) {
        int i = base + t;
        int v = (i < n) ? counts[i] : 0;
        sd[t] = v;
        __syncthreads();
        for (int off = 1; off < 1024; off <<= 1) {
            int tmp = (t >= off) ? sd[t - off] : 0;
            __syncthreads();
            sd[t] += tmp;
            __syncthreads();
        }
        int incl = sd[t];
        int total = sd[1023];
        if (i < n) {
            int excl = carry + incl - v;
            rowptr[i] = excl;
            cursor[i] = excl;
            dis[i] = 1.0f / sqrtf((float)(v + 1));
        }
        carry += total;
        __syncthreads();
    }
    if (t == 0) rowptr[n] = carry;
}

// Scatter edges into CSR (grouped by dst, storing src)
__global__ void k_scatter(const unsigned int* __restrict__ ew, const int* __restrict__ mode_p,
                          int* __restrict__ cursor, int* __restrict__ csr, int e) {
    int mode = *mode_p;
    int i = blockIdx.x * 256 + threadIdx.x;
    if (i >= e) return;
    int s, d;
    if (mode) {
        s = (int)ew[2 * (size_t)i];
        d = (int)ew[2 * ((size_t)e + i)];
    } else {
        s = (int)ew[(size_t)i];
        d = (int)ew[(size_t)e + i];
    }
    int pos = atomicAdd(&cursor[d], 1);
    csr[pos] = s;
}

// ---------------------------------------------------------------------------
// fp32 GEMM: C[M x 256] = A[M x K] @ B[K x 256] (+bias).
// A may be split in two source arrays along K (concat fusion for layer 1):
//   k < KA      -> A [row stride strideA]
//   k >= KA     -> A2[row stride strideA2], col (k - KA)
// Block: 64 rows x 256 cols (full width -> in-place safe: block owns rows).
// Thread tile 8x8, K-tile 16 staged in LDS.
// ---------------------------------------------------------------------------
#define BM 64
#define KT 16
template <bool ADD_BIAS>
__global__ __launch_bounds__(256) void k_gemm(const float* __restrict__ A, int strideA, int KA,
                                              const float* __restrict__ A2, int strideA2,
                                              const float* __restrict__ B,
                                              const float* __restrict__ bias,
                                              float* C, int M, int K) {
    __shared__ float As[KT][BM];       // k-major (transposed)
    __shared__ float Bs[KT][HID];
    int tid = threadIdx.x;
    int r0 = blockIdx.x * BM;
    int tr = (tid >> 5) * 8;           // 0..56
    int tc = (tid & 31) * 8;           // 0..248
    float acc[8][8] = {};

    for (int k0 = 0; k0 < K; k0 += KT) {
        // --- load A tile: 64 rows x 16 k; thread -> (row, 4 consecutive k)
        {
            int r = tid >> 2;            // 0..63
            int kq = (tid & 3) * 4;      // 0,4,8,12
            int row = r0 + r;
            int rr = row < M ? row : (M - 1);
            const float* src;
            int stride, kk0;
            if (k0 < KA) { src = A;  stride = strideA;  kk0 = k0; }
            else         { src = A2; stride = strideA2; kk0 = k0 - KA; }
            float4 a4 = *reinterpret_cast<const float4*>(&src[(size_t)rr * stride + kk0 + kq]);
            As[kq + 0][r] = a4.x;
            As[kq + 1][r] = a4.y;
            As[kq + 2][r] = a4.z;
            As[kq + 3][r] = a4.w;
        }
        // --- load B tile: 16 k x 256 cols
        {
            int c4 = (tid & 63) * 4;     // 0..252
            int kr0 = tid >> 6;          // 0..3
            for (int kk = kr0; kk < KT; kk += 4) {
                *reinterpret_cast<float4*>(&Bs[kk][c4]) =
                    *reinterpret_cast<const float4*>(&B[(size_t)(k0 + kk) * HID + c4]);
            }
        }
        __syncthreads();
        #pragma unroll
        for (int k = 0; k < KT; ++k) {
            float a[8], b[8];
            float4 a01 = *reinterpret_cast<const float4*>(&As[k][tr]);
            float4 a23 = *reinterpret_cast<const float4*>(&As[k][tr + 4]);
            a[0]=a01.x; a[1]=a01.y; a[2]=a01.z; a[3]=a01.w;
            a[4]=a23.x; a[5]=a23.y; a[6]=a23.z; a[7]=a23.w;
            float4 b01 = *reinterpret_cast<const float4*>(&Bs[k][tc]);
            float4 b23 = *reinterpret_cast<const float4*>(&Bs[k][tc + 4]);
            b[0]=b01.x; b[1]=b01.y; b[2]=b01.z; b[3]=b01.w;
            b[4]=b23.x; b[5]=b23.y; b[6]=b23.z; b[7]=b23.w;
            #pragma unroll
            for (int i = 0; i < 8; ++i)
                #pragma unroll
                for (int j = 0; j < 8; ++j)
                    acc[i][j] = fmaf(a[i], b[j], acc[i][j]);
        }
        __syncthreads();
    }

    // --- store (after full K loop -> in-place safe when C aliases A)
    #pragma unroll
    for (int i = 0; i < 8; ++i) {
        int row = r0 + tr + i;
        if (row < M) {
            #pragma unroll
            for (int j = 0; j < 8; j += 4) {
                float4 v;
                v.x = acc[i][j + 0]; v.y = acc[i][j + 1];
                v.z = acc[i][j + 2]; v.w = acc[i][j + 3];
                if (ADD_BIAS) {
                    v.x += bias[tc + j + 0]; v.y += bias[tc + j + 1];
                    v.z += bias[tc + j + 2]; v.w += bias[tc + j + 3];
                }
                *reinterpret_cast<float4*>(&C[(size_t)row * HID + tc + j]) = v;
            }
        }
    }
}

// ---------------------------------------------------------------------------
// Aggregation: out[i,c] = relu( sum_{e in CSR[i]} xin[src_e,c]*dis[src]*dis[i]
//                               + xin[i,c]*dis[i]^2 + bias[c] )
// One block (256 threads) per node; channel per thread; edges staged 64 at a
// time into LDS (index + precomputed weight).
// ---------------------------------------------------------------------------
__global__ __launch_bounds__(256) void k_agg(const float* __restrict__ xin,
                                             const int* __restrict__ rowptr,
                                             const int* __restrict__ csr,
                                             const float* __restrict__ dis,
                                             const float* __restrict__ bias,
                                             float* __restrict__ out, int n) {
    int i = blockIdx.x;
    int c = threadIdx.x;
    float disd = dis[i];
    int e0 = rowptr[i], e1 = rowptr[i + 1];
    float acc = xin[(size_t)i * HID + c] * disd * disd;

    __shared__ int   s_idx[64];
    __shared__ float s_w[64];
    for (int e = e0; e < e1; e += 64) {
        int cnt = min(64, e1 - e);
        __syncthreads();
        if (c < cnt) {
            int s = csr[e + c];
            s_idx[c] = s;
            s_w[c] = dis[s] * disd;
        }
        __syncthreads();
        for (int j = 0; j < cnt; ++j) {
            acc = fmaf(xin[(size_t)s_idx[j] * HID + c], s_w[j], acc);
        }
    }
    acc += bias[c];
    out[(size_t)i * HID + c] = fmaxf(acc, 0.0f);
}

// ---------------------------------------------------------------------------
extern "C" void kernel_launch(void* const* d_in, const int* in_sizes, int n_in,
                              void* d_out, int out_size, void* d_ws, size_t ws_size,
                              hipStream_t stream) {
    const float* x     = (const float*)d_in[0];
    const float* rni   = (const float*)d_in[1];
    const unsigned int* ew = (const unsigned int*)d_in[2];  // int32 or int64, sniffed
    const float* W1    = (const float*)d_in[3];
    const float* b1    = (const float*)d_in[4];
    const float* W2    = (const float*)d_in[5];
    const float* b2    = (const float*)d_in[6];
    const float* W_out = (const float*)d_in[7];
    const float* b_out = (const float*)d_in[8];
    float* out = (float*)d_out;

    const int n = in_sizes[0] / D_IN;      // 50000
    const int e = in_sizes[2] / 2;         // 800000

    // workspace carve-up
    char* ws = (char*)d_ws;
    size_t off = 0;
    auto carve = [&](size_t bytes) {
        char* p = ws + off;
        off = (off + bytes + 255) & ~(size_t)255;
        return p;
    };
    float* xbuf   = (float*)carve((size_t)n * HID * sizeof(float));  // 51.2 MB
    int*   counts = (int*)carve((size_t)n * sizeof(int));
    int*   rowptr = (int*)carve((size_t)(n + 1) * sizeof(int));
    int*   cursor = (int*)carve((size_t)n * sizeof(int));
    float* dis    = (float*)carve((size_t)n * sizeof(float));
    int*   csr    = (int*)carve((size_t)e * sizeof(int));
    int*   mode   = (int*)carve(sizeof(int));
    (void)ws_size;

    const int eb = (e + 255) / 256;
    const int gemm_blocks = (n + BM - 1) / BM;

    // --- CSR build
    k_detect<<<1, 256, 0, stream>>>(ew, 2 * e, mode);
    hipMemsetAsync(counts, 0, (size_t)n * sizeof(int), stream);
    k_count<<<eb, 256, 0, stream>>>(ew, mode, counts, e);
    k_scan<<<1, 1024, 0, stream>>>(counts, rowptr, cursor, dis, n);
    k_scatter<<<eb, 256, 0, stream>>>(ew, mode, cursor, csr, e);

    // --- layer 1: xbuf = [x|rni] @ W1 ; out(h1) = relu(agg(xbuf) + b1)
    k_gemm<false><<<gemm_blocks, 256, 0, stream>>>(x, D_IN, D_IN, rni, D_RNI,
                                                   W1, nullptr, xbuf, n, D_IN + D_RNI);
    k_agg<<<n, 256, 0, stream>>>(xbuf, rowptr, csr, dis, b1, out, n);

    // --- layer 2: xbuf = h1 @ W2 ; out(h2) = relu(agg(xbuf) + b2)
    k_gemm<false><<<gemm_blocks, 256, 0, stream>>>(out, HID, HID, nullptr, HID,
                                                   W2, nullptr, xbuf, n, HID);
    k_agg<<<n, 256, 0, stream>>>(xbuf, rowptr, csr, dis, b2, out, n);

    // --- output layer: out = h2 @ W_out + b_out (in-place; blocks own rows)
    k_gemm<true><<<gemm_blocks, 256, 0, stream>>>(out, HID, HID, nullptr, HID,
                                                  W_out, b_out, out, n, HID);
}

// Round 2
// 581.262 us; speedup vs baseline: 1.3677x; 1.3677x over previous
//
#include <hip/hip_runtime.h>
#include <hip/hip_bf16.h>
#include <hip/hip_fp16.h>
#include <math.h>

#define D_IN   128
#define D_RNI  32
#define HID    256

// ---------------------------------------------------------------------------
// Edge dtype detection: reference declares int64, but JAX without x64 yields
// int32. For int64 (values < 2^31), every odd 32-bit word is 0.
// ---------------------------------------------------------------------------
__global__ void k_detect(const unsigned int* __restrict__ w, int nwords, int* __restrict__ mode) {
    __shared__ unsigned int red[256];
    unsigned int acc = 0;
    for (int i = threadIdx.x; i < 1024; i += 256) {
        int idx = 2 * i + 1;
        if (idx < nwords) acc |= w[idx];
    }
    red[threadIdx.x] = acc;
    __syncthreads();
    for (int s = 128; s > 0; s >>= 1) {
        if (threadIdx.x < s) red[threadIdx.x] |= red[threadIdx.x + s];
        __syncthreads();
    }
    if (threadIdx.x == 0) *mode = (red[0] == 0u) ? 1 : 0;
}

__global__ void k_count(const unsigned int* __restrict__ ew, const int* __restrict__ mode_p,
                        int* __restrict__ counts, int e) {
    int mode = *mode_p;
    int i = blockIdx.x * 256 + threadIdx.x;
    if (i >= e) return;
    int d = mode ? (int)ew[2 * ((size_t)e + i)] : (int)ew[(size_t)e + i];
    atomicAdd(&counts[d], 1);
}

// ---------------------------------------------------------------------------
// Hierarchical scan (3 tiny kernels; replaces the 1-block serial scan that was
// suspected to burn O(100us) on a single CU).
// ---------------------------------------------------------------------------
__global__ __launch_bounds__(1024) void k_scan1(const int* __restrict__ counts,
                                                int* __restrict__ incl,
                                                int* __restrict__ bsum, int n) {
    __shared__ int sd[1024];
    int t = threadIdx.x;
    int i = blockIdx.x * 1024 + t;
    int v = (i < n) ? counts[i] : 0;
    sd[t] = v;
    __syncthreads();
    for (int off = 1; off < 1024; off <<= 1) {
        int tmp = (t >= off) ? sd[t - off] : 0;
        __syncthreads();
        sd[t] += tmp;
        __syncthreads();
    }
    if (i < n) incl[i] = sd[t];
    if (t == 1023) bsum[blockIdx.x] = sd[1023];
}

// Scan block sums (nb <= 1024); writes exclusive sums in-place + total at [nb].
__global__ __launch_bounds__(1024) void k_scan2(int* __restrict__ bsum, int nb) {
    __shared__ int sd[1024];
    int t = threadIdx.x;
    int v = (t < nb) ? bsum[t] : 0;
    sd[t] = v;
    __syncthreads();
    for (int off = 1; off < 1024; off <<= 1) {
        int tmp = (t >= off) ? sd[t - off] : 0;
        __syncthreads();
        sd[t] += tmp;
        __syncthreads();
    }
    if (t < nb) bsum[t] = sd[t] - v;          // exclusive
    if (t == nb - 1) bsum[nb] = sd[t];        // total
}

__global__ void k_scan3(const int* __restrict__ counts, const int* __restrict__ incl,
                        const int* __restrict__ bsum,
                        int* __restrict__ rowptr, int* __restrict__ cursor,
                        float* __restrict__ dis, int n, int nb) {
    int i = blockIdx.x * 256 + threadIdx.x;
    if (i >= n) return;
    int excl = incl[i] - counts[i] + bsum[i >> 10];
    rowptr[i] = excl;
    cursor[i] = excl;
    dis[i] = 1.0f / sqrtf((float)(counts[i] + 1));
    if (i == 0) rowptr[n] = bsum[nb];
}

__global__ void k_scatter(const unsigned int* __restrict__ ew, const int* __restrict__ mode_p,
                          int* __restrict__ cursor, int* __restrict__ csr, int e) {
    int mode = *mode_p;
    int i = blockIdx.x * 256 + threadIdx.x;
    if (i >= e) return;
    int s, d;
    if (mode) {
        s = (int)ew[2 * (size_t)i];
        d = (int)ew[2 * ((size_t)e + i)];
    } else {
        s = (int)ew[(size_t)i];
        d = (int)ew[(size_t)e + i];
    }
    int pos = atomicAdd(&cursor[d], 1);
    csr[pos] = s;
}

// ---------------------------------------------------------------------------
// fp32 GEMM: C[M x 256] = A[M x K] @ B[K x 256] (+bias).
// HALF_OUT: store result as fp16 (for the gather-heavy aggregation stage).
// 64-row x 256-col block (full width -> in-place safe), 8x8 thread tile, KT=16.
// ---------------------------------------------------------------------------
#define BM 64
#define KT 16
template <bool ADD_BIAS, bool HALF_OUT>
__global__ __launch_bounds__(256) void k_gemm(const float* __restrict__ A, int strideA, int KA,
                                              const float* __restrict__ A2, int strideA2,
                                              const float* __restrict__ B,
                                              const float* __restrict__ bias,
                                              void* Cv, int M, int K) {
    __shared__ float As[KT][BM];       // k-major
    __shared__ float Bs[KT][HID];
    int tid = threadIdx.x;
    int r0 = blockIdx.x * BM;
    int tr = (tid >> 5) * 8;
    int tc = (tid & 31) * 8;
    float acc[8][8] = {};

    for (int k0 = 0; k0 < K; k0 += KT) {
        {
            int r = tid >> 2;
            int kq = (tid & 3) * 4;
            int row = r0 + r;
            int rr = row < M ? row : (M - 1);
            const float* src;
            int stride, kk0;
            if (k0 < KA) { src = A;  stride = strideA;  kk0 = k0; }
            else         { src = A2; stride = strideA2; kk0 = k0 - KA; }
            float4 a4 = *reinterpret_cast<const float4*>(&src[(size_t)rr * stride + kk0 + kq]);
            As[kq + 0][r] = a4.x;
            As[kq + 1][r] = a4.y;
            As[kq + 2][r] = a4.z;
            As[kq + 3][r] = a4.w;
        }
        {
            int c4 = (tid & 63) * 4;
            int kr0 = tid >> 6;
            for (int kk = kr0; kk < KT; kk += 4) {
                *reinterpret_cast<float4*>(&Bs[kk][c4]) =
                    *reinterpret_cast<const float4*>(&B[(size_t)(k0 + kk) * HID + c4]);
            }
        }
        __syncthreads();
        #pragma unroll
        for (int k = 0; k < KT; ++k) {
            float a[8], b[8];
            float4 a01 = *reinterpret_cast<const float4*>(&As[k][tr]);
            float4 a23 = *reinterpret_cast<const float4*>(&As[k][tr + 4]);
            a[0]=a01.x; a[1]=a01.y; a[2]=a01.z; a[3]=a01.w;
            a[4]=a23.x; a[5]=a23.y; a[6]=a23.z; a[7]=a23.w;
            float4 b01 = *reinterpret_cast<const float4*>(&Bs[k][tc]);
            float4 b23 = *reinterpret_cast<const float4*>(&Bs[k][tc + 4]);
            b[0]=b01.x; b[1]=b01.y; b[2]=b01.z; b[3]=b01.w;
            b[4]=b23.x; b[5]=b23.y; b[6]=b23.z; b[7]=b23.w;
            #pragma unroll
            for (int i = 0; i < 8; ++i)
                #pragma unroll
                for (int j = 0; j < 8; ++j)
                    acc[i][j] = fmaf(a[i], b[j], acc[i][j]);
        }
        __syncthreads();
    }

    #pragma unroll
    for (int i = 0; i < 8; ++i) {
        int row = r0 + tr + i;
        if (row >= M) continue;
        #pragma unroll
        for (int j = 0; j < 8; j += 4) {
            float4 v;
            v.x = acc[i][j + 0]; v.y = acc[i][j + 1];
            v.z = acc[i][j + 2]; v.w = acc[i][j + 3];
            if (ADD_BIAS) {
                v.x += bias[tc + j + 0]; v.y += bias[tc + j + 1];
                v.z += bias[tc + j + 2]; v.w += bias[tc + j + 3];
            }
            if (HALF_OUT) {
                union { __half2 h2[2]; float2 f2; } u;
                u.h2[0] = __floats2half2_rn(v.x, v.y);
                u.h2[1] = __floats2half2_rn(v.z, v.w);
                *reinterpret_cast<float2*>(&((__half*)Cv)[(size_t)row * HID + tc + j]) = u.f2;
            } else {
                *reinterpret_cast<float4*>(&((float*)Cv)[(size_t)row * HID + tc + j]) = v;
            }
        }
    }
}

// ---------------------------------------------------------------------------
// Aggregation over fp16 features (halves gather traffic vs fp32):
// out[i,c] = relu( sum_e xh[src_e,c]*dis[src]*dis[i] + xh[i,c]*dis[i]^2 + b[c] )
// One 128-thread block per node; each thread owns 2 channels (half2 loads).
// ---------------------------------------------------------------------------
__global__ __launch_bounds__(128) void k_agg(const __half2* __restrict__ xh,
                                             const int* __restrict__ rowptr,
                                             const int* __restrict__ csr,
                                             const float* __restrict__ dis,
                                             const float* __restrict__ bias,
                                             float* __restrict__ out, int n) {
    int i = blockIdx.x;
    int c = threadIdx.x;                  // channel pair 0..127
    float disd = dis[i];
    int e0 = rowptr[i], e1 = rowptr[i + 1];
    float2 self = __half22float2(xh[(size_t)i * 128 + c]);
    float acc0 = self.x * disd * disd;
    float acc1 = self.y * disd * disd;

    __shared__ int   s_idx[128];
    __shared__ float s_w[128];
    for (int e = e0; e < e1; e += 128) {
        int cnt = min(128, e1 - e);
        __syncthreads();
        if (c < cnt) {
            int s = csr[e + c];
            s_idx[c] = s;
            s_w[c] = dis[s] * disd;
        }
        __syncthreads();
        int j = 0;
        for (; j + 4 <= cnt; j += 4) {
            float2 f0 = __half22float2(xh[(size_t)s_idx[j + 0] * 128 + c]);
            float2 f1 = __half22float2(xh[(size_t)s_idx[j + 1] * 128 + c]);
            float2 f2 = __half22float2(xh[(size_t)s_idx[j + 2] * 128 + c]);
            float2 f3 = __half22float2(xh[(size_t)s_idx[j + 3] * 128 + c]);
            acc0 = fmaf(f0.x, s_w[j + 0], acc0); acc1 = fmaf(f0.y, s_w[j + 0], acc1);
            acc0 = fmaf(f1.x, s_w[j + 1], acc0); acc1 = fmaf(f1.y, s_w[j + 1], acc1);
            acc0 = fmaf(f2.x, s_w[j + 2], acc0); acc1 = fmaf(f2.y, s_w[j + 2], acc1);
            acc0 = fmaf(f3.x, s_w[j + 3], acc0); acc1 = fmaf(f3.y, s_w[j + 3], acc1);
        }
        for (; j < cnt; ++j) {
            float2 f = __half22float2(xh[(size_t)s_idx[j] * 128 + c]);
            acc0 = fmaf(f.x, s_w[j], acc0);
            acc1 = fmaf(f.y, s_w[j], acc1);
        }
    }
    acc0 += bias[2 * c + 0];
    acc1 += bias[2 * c + 1];
    float2 o;
    o.x = fmaxf(acc0, 0.0f);
    o.y = fmaxf(acc1, 0.0f);
    reinterpret_cast<float2*>(out)[(size_t)i * 128 + c] = o;
}

// ---------------------------------------------------------------------------
extern "C" void kernel_launch(void* const* d_in, const int* in_sizes, int n_in,
                              void* d_out, int out_size, void* d_ws, size_t ws_size,
                              hipStream_t stream) {
    const float* x     = (const float*)d_in[0];
    const float* rni   = (const float*)d_in[1];
    const unsigned int* ew = (const unsigned int*)d_in[2];
    const float* W1    = (const float*)d_in[3];
    const float* b1    = (const float*)d_in[4];
    const float* W2    = (const float*)d_in[5];
    const float* b2    = (const float*)d_in[6];
    const float* W_out = (const float*)d_in[7];
    const float* b_out = (const float*)d_in[8];
    float* out = (float*)d_out;

    const int n = in_sizes[0] / D_IN;      // 50000
    const int e = in_sizes[2] / 2;         // 800000
    const int nb = (n + 1023) / 1024;      // scan blocks

    char* ws = (char*)d_ws;
    size_t off = 0;
    auto carve = [&](size_t bytes) {
        char* p = ws + off;
        off = (off + bytes + 255) & ~(size_t)255;
        return p;
    };
    __half* xh    = (__half*)carve((size_t)n * HID * sizeof(__half));  // 25.6 MB
    int*   counts = (int*)carve((size_t)n * sizeof(int));
    int*   incl   = (int*)carve((size_t)n * sizeof(int));
    int*   bsum   = (int*)carve((size_t)(nb + 1) * sizeof(int));
    int*   rowptr = (int*)carve((size_t)(n + 1) * sizeof(int));
    int*   cursor = (int*)carve((size_t)n * sizeof(int));
    float* dis    = (float*)carve((size_t)n * sizeof(float));
    int*   csr    = (int*)carve((size_t)e * sizeof(int));
    int*   mode   = (int*)carve(sizeof(int));
    (void)ws_size;

    const int eb = (e + 255) / 256;
    const int gemm_blocks = (n + BM - 1) / BM;

    // --- CSR build
    k_detect<<<1, 256, 0, stream>>>(ew, 2 * e, mode);
    hipMemsetAsync(counts, 0, (size_t)n * sizeof(int), stream);
    k_count<<<eb, 256, 0, stream>>>(ew, mode, counts, e);
    k_scan1<<<nb, 1024, 0, stream>>>(counts, incl, bsum, n);
    k_scan2<<<1, 1024, 0, stream>>>(bsum, nb);
    k_scan3<<<(n + 255) / 256, 256, 0, stream>>>(counts, incl, bsum, rowptr, cursor, dis, n, nb);
    k_scatter<<<eb, 256, 0, stream>>>(ew, mode, cursor, csr, e);

    // --- layer 1: xh = fp16([x|rni] @ W1) ; out = relu(agg(xh) + b1)
    k_gemm<false, true><<<gemm_blocks, 256, 0, stream>>>(x, D_IN, D_IN, rni, D_RNI,
                                                         W1, nullptr, xh, n, D_IN + D_RNI);
    k_agg<<<n, 128, 0, stream>>>((const __half2*)xh, rowptr, csr, dis, b1, out, n);

    // --- layer 2: xh = fp16(h1 @ W2) ; out = relu(agg(xh) + b2)
    k_gemm<false, true><<<gemm_blocks, 256, 0, stream>>>(out, HID, HID, nullptr, HID,
                                                         W2, nullptr, xh, n, HID);
    k_agg<<<n, 128, 0, stream>>>((const __half2*)xh, rowptr, csr, dis, b2, out, n);

    // --- output layer: out = h2 @ W_out + b_out (in-place fp32)
    k_gemm<true, false><<<gemm_blocks, 256, 0, stream>>>(out, HID, HID, nullptr, HID,
                                                         W_out, b_out, out, n, HID);
}

// Round 3
// 409.448 us; speedup vs baseline: 1.9416x; 1.4196x over previous
//
#include <hip/hip_runtime.h>
#include <hip/hip_bf16.h>
#include <hip/hip_fp16.h>
#include <math.h>

#define D_IN   128
#define D_RNI  32
#define HID    256

typedef _Float16 half8 __attribute__((ext_vector_type(8)));
typedef float    f32x4 __attribute__((ext_vector_type(4)));

// ---------------------------------------------------------------------------
// Edge dtype detection: int64 edges (values < 2^31) have all odd words zero.
// ---------------------------------------------------------------------------
__global__ void k_detect(const unsigned int* __restrict__ w, int nwords, int* __restrict__ mode) {
    __shared__ unsigned int red[256];
    unsigned int acc = 0;
    for (int i = threadIdx.x; i < 1024; i += 256) {
        int idx = 2 * i + 1;
        if (idx < nwords) acc |= w[idx];
    }
    red[threadIdx.x] = acc;
    __syncthreads();
    for (int s = 128; s > 0; s >>= 1) {
        if (threadIdx.x < s) red[threadIdx.x] |= red[threadIdx.x + s];
        __syncthreads();
    }
    if (threadIdx.x == 0) *mode = (red[0] == 0u) ? 1 : 0;
}

__global__ void k_count(const unsigned int* __restrict__ ew, const int* __restrict__ mode_p,
                        int* __restrict__ counts, int e) {
    int mode = *mode_p;
    int i = blockIdx.x * 256 + threadIdx.x;
    if (i >= e) return;
    int d = mode ? (int)ew[2 * ((size_t)e + i)] : (int)ew[(size_t)e + i];
    atomicAdd(&counts[d], 1);
}

// ---------------------------------------------------------------------------
// Hierarchical scan
// ---------------------------------------------------------------------------
__global__ __launch_bounds__(1024) void k_scan1(const int* __restrict__ counts,
                                                int* __restrict__ incl,
                                                int* __restrict__ bsum, int n) {
    __shared__ int sd[1024];
    int t = threadIdx.x;
    int i = blockIdx.x * 1024 + t;
    int v = (i < n) ? counts[i] : 0;
    sd[t] = v;
    __syncthreads();
    for (int off = 1; off < 1024; off <<= 1) {
        int tmp = (t >= off) ? sd[t - off] : 0;
        __syncthreads();
        sd[t] += tmp;
        __syncthreads();
    }
    if (i < n) incl[i] = sd[t];
    if (t == 1023) bsum[blockIdx.x] = sd[1023];
}

__global__ __launch_bounds__(1024) void k_scan2(int* __restrict__ bsum, int nb) {
    __shared__ int sd[1024];
    int t = threadIdx.x;
    int v = (t < nb) ? bsum[t] : 0;
    sd[t] = v;
    __syncthreads();
    for (int off = 1; off < 1024; off <<= 1) {
        int tmp = (t >= off) ? sd[t - off] : 0;
        __syncthreads();
        sd[t] += tmp;
        __syncthreads();
    }
    if (t < nb) bsum[t] = sd[t] - v;
    if (t == nb - 1) bsum[nb] = sd[t];
}

__global__ void k_scan3(const int* __restrict__ counts, const int* __restrict__ incl,
                        const int* __restrict__ bsum,
                        int* __restrict__ rowptr, int* __restrict__ cursor,
                        float* __restrict__ dis, int n, int nb) {
    int i = blockIdx.x * 256 + threadIdx.x;
    if (i >= n) return;
    int excl = incl[i] - counts[i] + bsum[i >> 10];
    rowptr[i] = excl;
    cursor[i] = excl;
    dis[i] = 1.0f / sqrtf((float)(counts[i] + 1));
    if (i == 0) rowptr[n] = bsum[nb];
}

__global__ void k_scatter(const unsigned int* __restrict__ ew, const int* __restrict__ mode_p,
                          int* __restrict__ cursor, int* __restrict__ csr, int e) {
    int mode = *mode_p;
    int i = blockIdx.x * 256 + threadIdx.x;
    if (i >= e) return;
    int s, d;
    if (mode) {
        s = (int)ew[2 * (size_t)i];
        d = (int)ew[2 * ((size_t)e + i)];
    } else {
        s = (int)ew[(size_t)i];
        d = (int)ew[(size_t)e + i];
    }
    int pos = atomicAdd(&cursor[d], 1);
    csr[pos] = s;
}

// ---------------------------------------------------------------------------
// fp32 -> fp16 column-block copy: dst[row][off + c] = fp16(src[row][c])
// ---------------------------------------------------------------------------
__global__ void k_cvt_cols(const float* __restrict__ src, int w4, __half* __restrict__ dst,
                           int dstw, int off, int total4) {
    int i = blockIdx.x * 256 + threadIdx.x;
    if (i >= total4) return;
    int row = i / w4;
    int c4 = (i - row * w4) * 4;
    float4 v = reinterpret_cast<const float4*>(src)[i];
    union { __half h[4]; float2 f2; } u;
    u.h[0] = __float2half(v.x); u.h[1] = __float2half(v.y);
    u.h[2] = __float2half(v.z); u.h[3] = __float2half(v.w);
    *reinterpret_cast<float2*>(&dst[(size_t)row * dstw + off + c4]) = u.f2;
}

// W[K][N] fp32 -> Wt[N][K] fp16 (transpose + cast; tiny matrices)
__global__ void k_cvt_wt(const float* __restrict__ W, __half* __restrict__ Wt,
                         int K, int N, int total) {
    int i = blockIdx.x * 256 + threadIdx.x;
    if (i >= total) return;
    int k = i / N, nn = i - k * N;
    Wt[(size_t)nn * K + k] = __float2half(W[i]);
}

// ---------------------------------------------------------------------------
// fp16 MFMA GEMM: C[M x 256] = A[M x K] @ Bt^T  (A:[M][K], Bt:[N=256][K], fp16)
// Block: 256 threads = 4 waves; tile 64 M x 256 N; wave w owns N in [64w,64w+64).
// v_mfma_f32_16x16x32_f16; A/B frag: row = lane&15, k = (lane>>4)*8 + j
// C/D: col = lane&15, row = (lane>>4)*4 + reg.
// LDS rows padded to 40 halves (80 B) -> even bank-quad spread on b128 ops.
// K must be a multiple of 32 (160 and 256 both are).
// ---------------------------------------------------------------------------
#define KT 32
#define LSTR 40
template <bool ADD_BIAS, bool HALF_OUT>
__global__ __launch_bounds__(256) void k_mgemm(const __half* __restrict__ A,
                                               const __half* __restrict__ Bt,
                                               const float* __restrict__ bias,
                                               void* Cv, int M, int K) {
    __shared__ __half As[64 * LSTR];
    __shared__ __half Bs[256 * LSTR];
    int tid = threadIdx.x;
    int wave = tid >> 6, lane = tid & 63;
    int q = lane >> 4, m16 = lane & 15;
    int r0 = blockIdx.x * 64;

    f32x4 acc[4][4] = {};

    for (int k0 = 0; k0 < K; k0 += KT) {
        __syncthreads();
        // stage A tile: 64 rows x 32 k
        {
            int r = tid >> 2, kq = (tid & 3) * 8;
            int row = r0 + r; if (row >= M) row = M - 1;
            uint4 v = *reinterpret_cast<const uint4*>(&A[(size_t)row * K + k0 + kq]);
            *reinterpret_cast<uint4*>(&As[r * LSTR + kq]) = v;
        }
        // stage B tile: 256 n x 32 k
        {
            int nb = tid >> 2, kq = (tid & 3) * 8;
            #pragma unroll
            for (int i = 0; i < 4; ++i) {
                int nn = nb + i * 64;
                uint4 v = *reinterpret_cast<const uint4*>(&Bt[(size_t)nn * K + k0 + kq]);
                *reinterpret_cast<uint4*>(&Bs[nn * LSTR + kq]) = v;
            }
        }
        __syncthreads();

        half8 af[4], bf[4];
        #pragma unroll
        for (int mi = 0; mi < 4; ++mi)
            af[mi] = *reinterpret_cast<const half8*>(&As[(mi * 16 + m16) * LSTR + q * 8]);
        #pragma unroll
        for (int ni = 0; ni < 4; ++ni)
            bf[ni] = *reinterpret_cast<const half8*>(&Bs[(wave * 64 + ni * 16 + m16) * LSTR + q * 8]);
        #pragma unroll
        for (int mi = 0; mi < 4; ++mi)
            #pragma unroll
            for (int ni = 0; ni < 4; ++ni)
                acc[mi][ni] = __builtin_amdgcn_mfma_f32_16x16x32_f16(af[mi], bf[ni], acc[mi][ni], 0, 0, 0);
    }

    // epilogue
    #pragma unroll
    for (int mi = 0; mi < 4; ++mi) {
        #pragma unroll
        for (int r = 0; r < 4; ++r) {
            int row = r0 + mi * 16 + q * 4 + r;
            if (row >= M) continue;
            #pragma unroll
            for (int ni = 0; ni < 4; ++ni) {
                int col = wave * 64 + ni * 16 + m16;
                float v = acc[mi][ni][r];
                if (ADD_BIAS) v += bias[col];
                if (HALF_OUT) ((__half*)Cv)[(size_t)row * HID + col] = __float2half(v);
                else          ((float*)Cv)[(size_t)row * HID + col] = v;
            }
        }
    }
}

// ---------------------------------------------------------------------------
// Aggregation over fp16 features; writes fp16:
// h[i,c] = relu( sum_e xh[src_e,c]*dis[src]*dis[i] + xh[i,c]*dis[i]^2 + b[c] )
// ---------------------------------------------------------------------------
__global__ __launch_bounds__(128) void k_agg(const __half2* __restrict__ xh,
                                             const int* __restrict__ rowptr,
                                             const int* __restrict__ csr,
                                             const float* __restrict__ dis,
                                             const float* __restrict__ bias,
                                             __half2* __restrict__ outh, int n) {
    int i = blockIdx.x;
    int c = threadIdx.x;                  // channel pair 0..127
    float disd = dis[i];
    int e0 = rowptr[i], e1 = rowptr[i + 1];
    float2 self = __half22float2(xh[(size_t)i * 128 + c]);
    float acc0 = self.x * disd * disd;
    float acc1 = self.y * disd * disd;

    __shared__ int   s_idx[128];
    __shared__ float s_w[128];
    for (int e = e0; e < e1; e += 128) {
        int cnt = min(128, e1 - e);
        __syncthreads();
        if (c < cnt) {
            int s = csr[e + c];
            s_idx[c] = s;
            s_w[c] = dis[s] * disd;
        }
        __syncthreads();
        int j = 0;
        for (; j + 4 <= cnt; j += 4) {
            float2 f0 = __half22float2(xh[(size_t)s_idx[j + 0] * 128 + c]);
            float2 f1 = __half22float2(xh[(size_t)s_idx[j + 1] * 128 + c]);
            float2 f2 = __half22float2(xh[(size_t)s_idx[j + 2] * 128 + c]);
            float2 f3 = __half22float2(xh[(size_t)s_idx[j + 3] * 128 + c]);
            acc0 = fmaf(f0.x, s_w[j + 0], acc0); acc1 = fmaf(f0.y, s_w[j + 0], acc1);
            acc0 = fmaf(f1.x, s_w[j + 1], acc0); acc1 = fmaf(f1.y, s_w[j + 1], acc1);
            acc0 = fmaf(f2.x, s_w[j + 2], acc0); acc1 = fmaf(f2.y, s_w[j + 2], acc1);
            acc0 = fmaf(f3.x, s_w[j + 3], acc0); acc1 = fmaf(f3.y, s_w[j + 3], acc1);
        }
        for (; j < cnt; ++j) {
            float2 f = __half22float2(xh[(size_t)s_idx[j] * 128 + c]);
            acc0 = fmaf(f.x, s_w[j], acc0);
            acc1 = fmaf(f.y, s_w[j], acc1);
        }
    }
    acc0 = fmaxf(acc0 + bias[2 * c + 0], 0.0f);
    acc1 = fmaxf(acc1 + bias[2 * c + 1], 0.0f);
    outh[(size_t)i * 128 + c] = __floats2half2_rn(acc0, acc1);
}

// ---------------------------------------------------------------------------
extern "C" void kernel_launch(void* const* d_in, const int* in_sizes, int n_in,
                              void* d_out, int out_size, void* d_ws, size_t ws_size,
                              hipStream_t stream) {
    const float* x     = (const float*)d_in[0];
    const float* rni   = (const float*)d_in[1];
    const unsigned int* ew = (const unsigned int*)d_in[2];
    const float* W1    = (const float*)d_in[3];
    const float* b1    = (const float*)d_in[4];
    const float* W2    = (const float*)d_in[5];
    const float* b2    = (const float*)d_in[6];
    const float* W_out = (const float*)d_in[7];
    const float* b_out = (const float*)d_in[8];
    float* out = (float*)d_out;

    const int n  = in_sizes[0] / D_IN;     // 50000
    const int e  = in_sizes[2] / 2;        // 800000
    const int nb = (n + 1023) / 1024;
    const int K1 = D_IN + D_RNI;           // 160

    char* ws = (char*)d_ws;
    size_t off = 0;
    auto carve = [&](size_t bytes) {
        char* p = ws + off;
        off = (off + bytes + 255) & ~(size_t)255;
        return p;
    };
    __half* xcat  = (__half*)carve((size_t)n * K1 * sizeof(__half));    // 16 MB
    __half* xh    = (__half*)carve((size_t)n * HID * sizeof(__half));   // 25.6 MB
    __half* h     = (__half*)carve((size_t)n * HID * sizeof(__half));   // 25.6 MB
    __half* W1t   = (__half*)carve((size_t)K1 * HID * sizeof(__half));
    __half* W2t   = (__half*)carve((size_t)HID * HID * sizeof(__half));
    __half* Wot   = (__half*)carve((size_t)HID * HID * sizeof(__half));
    int*   counts = (int*)carve((size_t)n * sizeof(int));
    int*   incl   = (int*)carve((size_t)n * sizeof(int));
    int*   bsum   = (int*)carve((size_t)(nb + 1) * sizeof(int));
    int*   rowptr = (int*)carve((size_t)(n + 1) * sizeof(int));
    int*   cursor = (int*)carve((size_t)n * sizeof(int));
    float* dis    = (float*)carve((size_t)n * sizeof(float));
    int*   csr    = (int*)carve((size_t)e * sizeof(int));
    int*   mode   = (int*)carve(sizeof(int));
    (void)ws_size;

    const int eb = (e + 255) / 256;
    const int gemm_blocks = (n + 63) / 64;

    // --- CSR build
    k_detect<<<1, 256, 0, stream>>>(ew, 2 * e, mode);
    hipMemsetAsync(counts, 0, (size_t)n * sizeof(int), stream);
    k_count<<<eb, 256, 0, stream>>>(ew, mode, counts, e);
    k_scan1<<<nb, 1024, 0, stream>>>(counts, incl, bsum, n);
    k_scan2<<<1, 1024, 0, stream>>>(bsum, nb);
    k_scan3<<<(n + 255) / 256, 256, 0, stream>>>(counts, incl, bsum, rowptr, cursor, dis, n, nb);
    k_scatter<<<eb, 256, 0, stream>>>(ew, mode, cursor, csr, e);

    // --- fp16 conversions: xcat = [x|rni], Wt = W^T
    {
        int t1 = n * (D_IN / 4);
        k_cvt_cols<<<(t1 + 255) / 256, 256, 0, stream>>>(x, D_IN / 4, xcat, K1, 0, t1);
        int t2 = n * (D_RNI / 4);
        k_cvt_cols<<<(t2 + 255) / 256, 256, 0, stream>>>(rni, D_RNI / 4, xcat, K1, D_IN, t2);
        int tw1 = K1 * HID;
        k_cvt_wt<<<(tw1 + 255) / 256, 256, 0, stream>>>(W1, W1t, K1, HID, tw1);
        int tw = HID * HID;
        k_cvt_wt<<<(tw + 255) / 256, 256, 0, stream>>>(W2, W2t, HID, HID, tw);
        k_cvt_wt<<<(tw + 255) / 256, 256, 0, stream>>>(W_out, Wot, HID, HID, tw);
    }

    // --- layer 1
    k_mgemm<false, true><<<gemm_blocks, 256, 0, stream>>>(xcat, W1t, nullptr, xh, n, K1);
    k_agg<<<n, 128, 0, stream>>>((const __half2*)xh, rowptr, csr, dis, b1, (__half2*)h, n);

    // --- layer 2
    k_mgemm<false, true><<<gemm_blocks, 256, 0, stream>>>(h, W2t, nullptr, xh, n, HID);
    k_agg<<<n, 128, 0, stream>>>((const __half2*)xh, rowptr, csr, dis, b2, (__half2*)h, n);

    // --- output layer (fp32 out + bias)
    k_mgemm<true, false><<<gemm_blocks, 256, 0, stream>>>(h, Wot, b_out, out, n, HID);
}

// Round 4
// 390.388 us; speedup vs baseline: 2.0364x; 1.0488x over previous
//
#include <hip/hip_runtime.h>
#include <hip/hip_bf16.h>
#include <hip/hip_fp16.h>
#include <math.h>

#define D_IN   128
#define D_RNI  32
#define HID    256

typedef _Float16 half8 __attribute__((ext_vector_type(8)));
typedef float    f32x4 __attribute__((ext_vector_type(4)));

// ---------------------------------------------------------------------------
// Edge dtype detection: int64 edges (values < 2^31) have all odd words zero.
// ---------------------------------------------------------------------------
__global__ void k_detect(const unsigned int* __restrict__ w, int nwords, int* __restrict__ mode) {
    __shared__ unsigned int red[256];
    unsigned int acc = 0;
    for (int i = threadIdx.x; i < 1024; i += 256) {
        int idx = 2 * i + 1;
        if (idx < nwords) acc |= w[idx];
    }
    red[threadIdx.x] = acc;
    __syncthreads();
    for (int s = 128; s > 0; s >>= 1) {
        if (threadIdx.x < s) red[threadIdx.x] |= red[threadIdx.x + s];
        __syncthreads();
    }
    if (threadIdx.x == 0) *mode = (red[0] == 0u) ? 1 : 0;
}

__global__ void k_count(const unsigned int* __restrict__ ew, const int* __restrict__ mode_p,
                        int* __restrict__ counts, int e) {
    int mode = *mode_p;
    int i = blockIdx.x * 256 + threadIdx.x;
    if (i >= e) return;
    int d = mode ? (int)ew[2 * ((size_t)e + i)] : (int)ew[(size_t)e + i];
    atomicAdd(&counts[d], 1);
}

// ---------------------------------------------------------------------------
// Hierarchical scan
// ---------------------------------------------------------------------------
__global__ __launch_bounds__(1024) void k_scan1(const int* __restrict__ counts,
                                                int* __restrict__ incl,
                                                int* __restrict__ bsum, int n) {
    __shared__ int sd[1024];
    int t = threadIdx.x;
    int i = blockIdx.x * 1024 + t;
    int v = (i < n) ? counts[i] : 0;
    sd[t] = v;
    __syncthreads();
    for (int off = 1; off < 1024; off <<= 1) {
        int tmp = (t >= off) ? sd[t - off] : 0;
        __syncthreads();
        sd[t] += tmp;
        __syncthreads();
    }
    if (i < n) incl[i] = sd[t];
    if (t == 1023) bsum[blockIdx.x] = sd[1023];
}

__global__ __launch_bounds__(1024) void k_scan2(int* __restrict__ bsum, int nb) {
    __shared__ int sd[1024];
    int t = threadIdx.x;
    int v = (t < nb) ? bsum[t] : 0;
    sd[t] = v;
    __syncthreads();
    for (int off = 1; off < 1024; off <<= 1) {
        int tmp = (t >= off) ? sd[t - off] : 0;
        __syncthreads();
        sd[t] += tmp;
        __syncthreads();
    }
    if (t < nb) bsum[t] = sd[t] - v;
    if (t == nb - 1) bsum[nb] = sd[t];
}

__global__ void k_scan3(const int* __restrict__ counts, const int* __restrict__ incl,
                        const int* __restrict__ bsum,
                        int* __restrict__ rowptr, int* __restrict__ cursor,
                        float* __restrict__ dis, int n, int nb) {
    int i = blockIdx.x * 256 + threadIdx.x;
    if (i >= n) return;
    int excl = incl[i] - counts[i] + bsum[i >> 10];
    rowptr[i] = excl;
    cursor[i] = excl;
    dis[i] = 1.0f / sqrtf((float)(counts[i] + 1));
    if (i == 0) rowptr[n] = bsum[nb];
}

__global__ void k_scatter(const unsigned int* __restrict__ ew, const int* __restrict__ mode_p,
                          int* __restrict__ cursor, int* __restrict__ csr, int e) {
    int mode = *mode_p;
    int i = blockIdx.x * 256 + threadIdx.x;
    if (i >= e) return;
    int s, d;
    if (mode) {
        s = (int)ew[2 * (size_t)i];
        d = (int)ew[2 * ((size_t)e + i)];
    } else {
        s = (int)ew[(size_t)i];
        d = (int)ew[(size_t)e + i];
    }
    int pos = atomicAdd(&cursor[d], 1);
    csr[pos] = s;
}

// W[K][N] fp32 -> Wt[N][K] fp16 (transpose + cast; tiny matrices)
__global__ void k_cvt_wt(const float* __restrict__ W, __half* __restrict__ Wt,
                         int K, int N, int total) {
    int i = blockIdx.x * 256 + threadIdx.x;
    if (i >= total) return;
    int k = i / N, nn = i - k * N;
    Wt[(size_t)nn * K + k] = __float2half(W[i]);
}

// ---------------------------------------------------------------------------
// fp16 MFMA GEMM: C[M x 256] = A[M x K] @ Bt^T  (Bt:[N=256][K] fp16).
// A_F32: A (and optional A2, concat along K at KA) are fp32, converted to fp16
// during LDS staging (fuses the input cast; K-split KA must be KT-aligned).
// Block: 256 threads = 4 waves; tile 64 M x 256 N; wave w owns N [64w, 64w+64).
// v_mfma_f32_16x16x32_f16; LDS rows padded to 40 halves (no 4-way+ conflicts).
// ---------------------------------------------------------------------------
#define KT 32
#define LSTR 40
template <bool A_F32, bool ADD_BIAS, bool HALF_OUT>
__global__ __launch_bounds__(256) void k_mgemm(const void* __restrict__ Av, int strideA, int KA,
                                               const void* __restrict__ A2v, int strideA2,
                                               const __half* __restrict__ Bt,
                                               const float* __restrict__ bias,
                                               void* Cv, int M, int K) {
    __shared__ __half As[64 * LSTR];
    __shared__ __half Bs[256 * LSTR];
    int tid = threadIdx.x;
    int wave = tid >> 6, lane = tid & 63;
    int q = lane >> 4, m16 = lane & 15;
    int r0 = blockIdx.x * 64;

    f32x4 acc[4][4] = {};

    for (int k0 = 0; k0 < K; k0 += KT) {
        __syncthreads();
        // stage A tile: 64 rows x 32 k (8 halves per thread)
        {
            int r = tid >> 2, kq = (tid & 3) * 8;
            int row = r0 + r; if (row >= M) row = M - 1;
            if (A_F32) {
                const float* src; int stride, kk0;
                if (k0 < KA) { src = (const float*)Av;  stride = strideA;  kk0 = k0; }
                else         { src = (const float*)A2v; stride = strideA2; kk0 = k0 - KA; }
                const float* p = &src[(size_t)row * stride + kk0 + kq];
                float4 va = *reinterpret_cast<const float4*>(p);
                float4 vb = *reinterpret_cast<const float4*>(p + 4);
                union { __half2 h2[4]; uint4 u; } uu;
                uu.h2[0] = __floats2half2_rn(va.x, va.y);
                uu.h2[1] = __floats2half2_rn(va.z, va.w);
                uu.h2[2] = __floats2half2_rn(vb.x, vb.y);
                uu.h2[3] = __floats2half2_rn(vb.z, vb.w);
                *reinterpret_cast<uint4*>(&As[r * LSTR + kq]) = uu.u;
            } else {
                const __half* src = (const __half*)Av;
                uint4 v = *reinterpret_cast<const uint4*>(&src[(size_t)row * strideA + k0 + kq]);
                *reinterpret_cast<uint4*>(&As[r * LSTR + kq]) = v;
            }
        }
        // stage B tile: 256 n x 32 k
        {
            int nb = tid >> 2, kq = (tid & 3) * 8;
            #pragma unroll
            for (int i = 0; i < 4; ++i) {
                int nn = nb + i * 64;
                uint4 v = *reinterpret_cast<const uint4*>(&Bt[(size_t)nn * K + k0 + kq]);
                *reinterpret_cast<uint4*>(&Bs[nn * LSTR + kq]) = v;
            }
        }
        __syncthreads();

        half8 af[4], bf[4];
        #pragma unroll
        for (int mi = 0; mi < 4; ++mi)
            af[mi] = *reinterpret_cast<const half8*>(&As[(mi * 16 + m16) * LSTR + q * 8]);
        #pragma unroll
        for (int ni = 0; ni < 4; ++ni)
            bf[ni] = *reinterpret_cast<const half8*>(&Bs[(wave * 64 + ni * 16 + m16) * LSTR + q * 8]);
        #pragma unroll
        for (int mi = 0; mi < 4; ++mi)
            #pragma unroll
            for (int ni = 0; ni < 4; ++ni)
                acc[mi][ni] = __builtin_amdgcn_mfma_f32_16x16x32_f16(af[mi], bf[ni], acc[mi][ni], 0, 0, 0);
    }

    // epilogue
    #pragma unroll
    for (int mi = 0; mi < 4; ++mi) {
        #pragma unroll
        for (int r = 0; r < 4; ++r) {
            int row = r0 + mi * 16 + q * 4 + r;
            if (row >= M) continue;
            #pragma unroll
            for (int ni = 0; ni < 4; ++ni) {
                int col = wave * 64 + ni * 16 + m16;
                float v = acc[mi][ni][r];
                if (ADD_BIAS) v += bias[col];
                if (HALF_OUT) ((__half*)Cv)[(size_t)row * HID + col] = __float2half(v);
                else          ((float*)Cv)[(size_t)row * HID + col] = v;
            }
        }
    }
}

// ---------------------------------------------------------------------------
// Aggregation, wave-per-node, barrier-free:
// h[i,c] = relu( sum_e xh[src_e,c]*dis[src]*dis[i] + xh[i,c]*dis[i]^2 + b[c] )
// 256-thread block = 4 waves = 4 nodes. Lane owns 4 channels (one 8B load per
// edge). Edge idx/weight staged in registers, broadcast via __shfl. 4-edge
// unroll -> 4 independent 8B loads in flight per lane.
// ---------------------------------------------------------------------------
__global__ __launch_bounds__(256) void k_agg(const __half* __restrict__ xh,
                                             const int* __restrict__ rowptr,
                                             const int* __restrict__ csr,
                                             const float* __restrict__ dis,
                                             const float* __restrict__ bias,
                                             __half* __restrict__ outh, int n) {
    int i = blockIdx.x * 4 + (threadIdx.x >> 6);
    if (i >= n) return;
    int lane = threadIdx.x & 63;
    int c4 = lane * 4;
    float disd = dis[i];
    int e0 = rowptr[i], e1 = rowptr[i + 1];

    float acc0, acc1, acc2, acc3;
    {
        uint2 v = *reinterpret_cast<const uint2*>(&xh[(size_t)i * HID + c4]);
        float2 f0 = __half22float2(*reinterpret_cast<__half2*>(&v.x));
        float2 f1 = __half22float2(*reinterpret_cast<__half2*>(&v.y));
        float ws = disd * disd;
        acc0 = f0.x * ws; acc1 = f0.y * ws; acc2 = f1.x * ws; acc3 = f1.y * ws;
    }

    for (int e = e0; e < e1; e += 64) {
        int cnt = min(64, e1 - e);
        int sreg = 0; float wreg = 0.0f;
        if (lane < cnt) {
            sreg = csr[e + lane];
            wreg = dis[sreg] * disd;
        }
        int j = 0;
        for (; j + 4 <= cnt; j += 4) {
            int   s0 = __shfl(sreg, j + 0), s1 = __shfl(sreg, j + 1);
            int   s2 = __shfl(sreg, j + 2), s3 = __shfl(sreg, j + 3);
            float w0 = __shfl(wreg, j + 0), w1 = __shfl(wreg, j + 1);
            float w2 = __shfl(wreg, j + 2), w3 = __shfl(wreg, j + 3);
            uint2 v0 = *reinterpret_cast<const uint2*>(&xh[(size_t)s0 * HID + c4]);
            uint2 v1 = *reinterpret_cast<const uint2*>(&xh[(size_t)s1 * HID + c4]);
            uint2 v2 = *reinterpret_cast<const uint2*>(&xh[(size_t)s2 * HID + c4]);
            uint2 v3 = *reinterpret_cast<const uint2*>(&xh[(size_t)s3 * HID + c4]);
            float2 a0 = __half22float2(*reinterpret_cast<__half2*>(&v0.x));
            float2 b0 = __half22float2(*reinterpret_cast<__half2*>(&v0.y));
            float2 a1 = __half22float2(*reinterpret_cast<__half2*>(&v1.x));
            float2 b1 = __half22float2(*reinterpret_cast<__half2*>(&v1.y));
            float2 a2 = __half22float2(*reinterpret_cast<__half2*>(&v2.x));
            float2 b2 = __half22float2(*reinterpret_cast<__half2*>(&v2.y));
            float2 a3 = __half22float2(*reinterpret_cast<__half2*>(&v3.x));
            float2 b3 = __half22float2(*reinterpret_cast<__half2*>(&v3.y));
            acc0 = fmaf(a0.x, w0, acc0); acc1 = fmaf(a0.y, w0, acc1);
            acc2 = fmaf(b0.x, w0, acc2); acc3 = fmaf(b0.y, w0, acc3);
            acc0 = fmaf(a1.x, w1, acc0); acc1 = fmaf(a1.y, w1, acc1);
            acc2 = fmaf(b1.x, w1, acc2); acc3 = fmaf(b1.y, w1, acc3);
            acc0 = fmaf(a2.x, w2, acc0); acc1 = fmaf(a2.y, w2, acc1);
            acc2 = fmaf(b2.x, w2, acc2); acc3 = fmaf(b2.y, w2, acc3);
            acc0 = fmaf(a3.x, w3, acc0); acc1 = fmaf(a3.y, w3, acc1);
            acc2 = fmaf(b3.x, w3, acc2); acc3 = fmaf(b3.y, w3, acc3);
        }
        for (; j < cnt; ++j) {
            int   s = __shfl(sreg, j);
            float w = __shfl(wreg, j);
            uint2 v = *reinterpret_cast<const uint2*>(&xh[(size_t)s * HID + c4]);
            float2 a = __half22float2(*reinterpret_cast<__half2*>(&v.x));
            float2 b = __half22float2(*reinterpret_cast<__half2*>(&v.y));
            acc0 = fmaf(a.x, w, acc0); acc1 = fmaf(a.y, w, acc1);
            acc2 = fmaf(b.x, w, acc2); acc3 = fmaf(b.y, w, acc3);
        }
    }

    float4 bb = *reinterpret_cast<const float4*>(&bias[c4]);
    union { __half2 h2[2]; uint2 u; } o;
    o.h2[0] = __floats2half2_rn(fmaxf(acc0 + bb.x, 0.0f), fmaxf(acc1 + bb.y, 0.0f));
    o.h2[1] = __floats2half2_rn(fmaxf(acc2 + bb.z, 0.0f), fmaxf(acc3 + bb.w, 0.0f));
    *reinterpret_cast<uint2*>(&outh[(size_t)i * HID + c4]) = o.u;
}

// ---------------------------------------------------------------------------
extern "C" void kernel_launch(void* const* d_in, const int* in_sizes, int n_in,
                              void* d_out, int out_size, void* d_ws, size_t ws_size,
                              hipStream_t stream) {
    const float* x     = (const float*)d_in[0];
    const float* rni   = (const float*)d_in[1];
    const unsigned int* ew = (const unsigned int*)d_in[2];
    const float* W1    = (const float*)d_in[3];
    const float* b1    = (const float*)d_in[4];
    const float* W2    = (const float*)d_in[5];
    const float* b2    = (const float*)d_in[6];
    const float* W_out = (const float*)d_in[7];
    const float* b_out = (const float*)d_in[8];
    float* out = (float*)d_out;

    const int n  = in_sizes[0] / D_IN;     // 50000
    const int e  = in_sizes[2] / 2;        // 800000
    const int nb = (n + 1023) / 1024;
    const int K1 = D_IN + D_RNI;           // 160

    char* ws = (char*)d_ws;
    size_t off = 0;
    auto carve = [&](size_t bytes) {
        char* p = ws + off;
        off = (off + bytes + 255) & ~(size_t)255;
        return p;
    };
    __half* xh    = (__half*)carve((size_t)n * HID * sizeof(__half));   // 25.6 MB
    __half* h     = (__half*)carve((size_t)n * HID * sizeof(__half));   // 25.6 MB
    __half* W1t   = (__half*)carve((size_t)K1 * HID * sizeof(__half));
    __half* W2t   = (__half*)carve((size_t)HID * HID * sizeof(__half));
    __half* Wot   = (__half*)carve((size_t)HID * HID * sizeof(__half));
    int*   counts = (int*)carve((size_t)n * sizeof(int));
    int*   incl   = (int*)carve((size_t)n * sizeof(int));
    int*   bsum   = (int*)carve((size_t)(nb + 1) * sizeof(int));
    int*   rowptr = (int*)carve((size_t)(n + 1) * sizeof(int));
    int*   cursor = (int*)carve((size_t)n * sizeof(int));
    float* dis    = (float*)carve((size_t)n * sizeof(float));
    int*   csr    = (int*)carve((size_t)e * sizeof(int));
    int*   mode   = (int*)carve(sizeof(int));
    (void)ws_size;

    const int eb = (e + 255) / 256;
    const int gemm_blocks = (n + 63) / 64;
    const int agg_blocks  = (n + 3) / 4;

    // --- CSR build
    k_detect<<<1, 256, 0, stream>>>(ew, 2 * e, mode);
    hipMemsetAsync(counts, 0, (size_t)n * sizeof(int), stream);
    k_count<<<eb, 256, 0, stream>>>(ew, mode, counts, e);
    k_scan1<<<nb, 1024, 0, stream>>>(counts, incl, bsum, n);
    k_scan2<<<1, 1024, 0, stream>>>(bsum, nb);
    k_scan3<<<(n + 255) / 256, 256, 0, stream>>>(counts, incl, bsum, rowptr, cursor, dis, n, nb);
    k_scatter<<<eb, 256, 0, stream>>>(ew, mode, cursor, csr, e);

    // --- weight transposes (tiny)
    {
        int tw1 = K1 * HID;
        k_cvt_wt<<<(tw1 + 255) / 256, 256, 0, stream>>>(W1, W1t, K1, HID, tw1);
        int tw = HID * HID;
        k_cvt_wt<<<(tw + 255) / 256, 256, 0, stream>>>(W2, W2t, HID, HID, tw);
        k_cvt_wt<<<(tw + 255) / 256, 256, 0, stream>>>(W_out, Wot, HID, HID, tw);
    }

    // --- layer 1 (fp32 inputs converted in GEMM staging)
    k_mgemm<true, false, true><<<gemm_blocks, 256, 0, stream>>>(x, D_IN, D_IN, rni, D_RNI,
                                                                W1t, nullptr, xh, n, K1);
    k_agg<<<agg_blocks, 256, 0, stream>>>(xh, rowptr, csr, dis, b1, h, n);

    // --- layer 2
    k_mgemm<false, false, true><<<gemm_blocks, 256, 0, stream>>>(h, HID, HID, nullptr, 0,
                                                                 W2t, nullptr, xh, n, HID);
    k_agg<<<agg_blocks, 256, 0, stream>>>(xh, rowptr, csr, dis, b2, h, n);

    // --- output layer (fp32 out + bias)
    k_mgemm<false, true, false><<<gemm_blocks, 256, 0, stream>>>(h, HID, HID, nullptr, 0,
                                                                 Wot, b_out, out, n, HID);
}